// Round 6
// baseline (370.371 us; speedup 1.0000x reference)
//
#include <hip/hip_runtime.h>
#include <hip/hip_bf16.h>

__device__ __forceinline__ float eluf(float x) {
    return x > 0.f ? x : expm1f(x);
}

// C[M,N] = act( A[M,K] @ B[N,K]^T + bias ), ACT: 0 none, 1 relu.
// SPLIT: raw partial to C + blockIdx.z*M*N over K-chunk [z*kChunk, +kChunk)
template<int ACT, bool BIAS, bool SPLIT>
__global__ __launch_bounds__(256) void gemm256(
    const float* __restrict__ A, const float* __restrict__ B,
    const float* __restrict__ bias, float* __restrict__ C,
    int M, int N, int K, int kChunk)
{
    constexpr int BM = 64, BN = 64, BK = 16;
    __shared__ float As[BK][BM + 4];
    __shared__ float Bs[BK][BN + 4];
    const int t  = threadIdx.x;
    const int tx = t & 15;
    const int ty = t >> 4;
    const int m0 = blockIdx.x * BM;
    const int n0 = blockIdx.y * BN;
    const int kBeg = SPLIT ? blockIdx.z * kChunk : 0;
    const int kEnd = SPLIT ? kBeg + kChunk : K;

    const int sr = t >> 2;
    const int sc = t & 3;

    float acc[4][4] = {};

    for (int k0 = kBeg; k0 < kEnd; k0 += BK) {
        {
            int row = m0 + sr;
            float4 v = make_float4(0.f, 0.f, 0.f, 0.f);
            if (row < M) v = *(const float4*)&A[(size_t)row * K + k0 + sc * 4];
            As[sc * 4 + 0][sr] = v.x; As[sc * 4 + 1][sr] = v.y;
            As[sc * 4 + 2][sr] = v.z; As[sc * 4 + 3][sr] = v.w;
        }
        {
            float4 v = *(const float4*)&B[(size_t)(n0 + sr) * K + k0 + sc * 4];
            Bs[sc * 4 + 0][sr] = v.x; Bs[sc * 4 + 1][sr] = v.y;
            Bs[sc * 4 + 2][sr] = v.z; Bs[sc * 4 + 3][sr] = v.w;
        }
        __syncthreads();
        #pragma unroll
        for (int k = 0; k < BK; ++k) {
            float a[4], b[4];
            *(float4*)&a[0] = *(const float4*)&As[k][ty * 4];
            *(float4*)&b[0] = *(const float4*)&Bs[k][tx * 4];
            #pragma unroll
            for (int i = 0; i < 4; ++i)
                #pragma unroll
                for (int j = 0; j < 4; ++j)
                    acc[i][j] = fmaf(a[i], b[j], acc[i][j]);
        }
        __syncthreads();
    }

    float* Cw = SPLIT ? C + (size_t)blockIdx.z * M * N : C;
    #pragma unroll
    for (int i = 0; i < 4; ++i) {
        int row = m0 + ty * 4 + i;
        if (row >= M) continue;
        float4 v;
        float* vp = (float*)&v;
        #pragma unroll
        for (int j = 0; j < 4; ++j) {
            float xv = acc[i][j];
            if (!SPLIT) {
                if (BIAS) xv += bias[n0 + tx * 4 + j];
                if (ACT == 1) xv = fmaxf(xv, 0.f);
            }
            vp[j] = xv;
        }
        *(float4*)&Cw[(size_t)row * N + n0 + tx * 4] = v;
    }
}

// ---------- fused layer1+layer2-GEMM ----------
// Per 64-node block: As = gather-sum(x) ; acc = As@W1^T ; As = elu(acc) ;
// z2 = As@W2^T.  h1 is never materialized.
__global__ __launch_bounds__(256) void gat_layer12(
    const int* __restrict__ ell, const int* __restrict__ cnt,
    const float* __restrict__ x, const float* __restrict__ W1,
    const float* __restrict__ W2, float* __restrict__ z2, int N)
{
    __shared__ float As[64][132];   // [node][k], 33.8 KB
    __shared__ float Ws[16][132];   // [k][n],    8.4 KB
    const int t   = threadIdx.x;
    const int nt0 = blockIdx.x * 64;

    // ---- phase 1: gather-sum x into As (8 groups x 32 lanes, 8 nodes each)
    {
        const int gi = t >> 5;
        const int lane = t & 31;
        for (int s = 0; s < 8; ++s) {
            int nl = gi * 8 + s;
            int node = nt0 + nl;
            float ax = 0.f, ay = 0.f, az = 0.f, aw = 0.f;
            if (node < N) {
                int deg = cnt[node];
                size_t base = (size_t)node * 64;
                for (int b0 = 0; b0 < deg; b0 += 32) {
                    int c = (b0 + lane < deg) ? ell[base + b0 + lane] : 0;
                    int m = min(32, deg - b0);
                    for (int j = 0; j < m; ++j) {
                        int cj = __shfl(c, j, 32);
                        float4 v = *(const float4*)&x[(size_t)cj * 128 + lane * 4];
                        ax += v.x; ay += v.y; az += v.z; aw += v.w;
                    }
                }
            }
            *(float4*)&As[nl][lane * 4] = make_float4(ax, ay, az, aw);
        }
    }
    __syncthreads();

    const int tx = t & 15, ty = t >> 4;   // 4 rows (ty*4+i), cols tx+16*j

    // ---- phase 2: GEMM1 (K=128, N=128), W1 streamed in 16-k tiles
    float acc[4][8] = {};
    for (int k0 = 0; k0 < 128; k0 += 16) {
        for (int idx = t; idx < 512; idx += 256) {       // 128 n x 4 kq
            int n = idx >> 2, kq = idx & 3;
            float4 v = *(const float4*)&W1[(size_t)n * 128 + k0 + kq * 4];
            Ws[kq * 4 + 0][n] = v.x; Ws[kq * 4 + 1][n] = v.y;
            Ws[kq * 4 + 2][n] = v.z; Ws[kq * 4 + 3][n] = v.w;
        }
        __syncthreads();
        #pragma unroll
        for (int k = 0; k < 16; ++k) {
            float a[4], w[8];
            #pragma unroll
            for (int i = 0; i < 4; ++i) a[i] = As[ty * 4 + i][k0 + k];
            #pragma unroll
            for (int j = 0; j < 8; ++j) w[j] = Ws[k][tx + 16 * j];
            #pragma unroll
            for (int i = 0; i < 4; ++i)
                #pragma unroll
                for (int j = 0; j < 8; ++j)
                    acc[i][j] = fmaf(a[i], w[j], acc[i][j]);
        }
        __syncthreads();
    }

    // ---- phase 3: As = elu(h1 tile)
    #pragma unroll
    for (int i = 0; i < 4; ++i)
        #pragma unroll
        for (int j = 0; j < 8; ++j)
            As[ty * 4 + i][tx + 16 * j] = eluf(acc[i][j]);
    __syncthreads();

    // ---- phase 4: GEMM2 (K=128, N=64), W2 streamed
    float acc2[4][4] = {};
    for (int k0 = 0; k0 < 128; k0 += 16) {
        for (int idx = t; idx < 256; idx += 256) {       // 64 n x 4 kq
            int n = idx >> 2, kq = idx & 3;
            float4 v = *(const float4*)&W2[(size_t)n * 128 + k0 + kq * 4];
            Ws[kq * 4 + 0][n] = v.x; Ws[kq * 4 + 1][n] = v.y;
            Ws[kq * 4 + 2][n] = v.z; Ws[kq * 4 + 3][n] = v.w;
        }
        __syncthreads();
        #pragma unroll
        for (int k = 0; k < 16; ++k) {
            float a[4], w[4];
            #pragma unroll
            for (int i = 0; i < 4; ++i) a[i] = As[ty * 4 + i][k0 + k];
            #pragma unroll
            for (int j = 0; j < 4; ++j) w[j] = Ws[k][tx + 16 * j];
            #pragma unroll
            for (int i = 0; i < 4; ++i)
                #pragma unroll
                for (int j = 0; j < 4; ++j)
                    acc2[i][j] = fmaf(a[i], w[j], acc2[i][j]);
        }
        __syncthreads();
    }

    #pragma unroll
    for (int i = 0; i < 4; ++i) {
        int row = nt0 + ty * 4 + i;
        if (row >= N) continue;
        #pragma unroll
        for (int j = 0; j < 4; ++j)
            z2[(size_t)row * 64 + tx + 16 * j] = acc2[i][j];
    }
}

// C[i] = relu( sum_z part[z][i] + bias[i % N] ), float4-wide
__global__ __launch_bounds__(256) void reduce_bias_relu(
    const float* __restrict__ part, const float* __restrict__ bias,
    float* __restrict__ C, int MN4, int N, int KS)
{
    int i = blockIdx.x * 256 + threadIdx.x;
    if (i >= MN4) return;
    float4 s = *(const float4*)&part[(size_t)i * 4];
    for (int z = 1; z < KS; ++z) {
        float4 p = *(const float4*)&part[(size_t)z * MN4 * 4 + (size_t)i * 4];
        s.x += p.x; s.y += p.y; s.z += p.z; s.w += p.w;
    }
    float4 bv = *(const float4*)&bias[(i * 4) & (N - 1)];
    s.x = fmaxf(s.x + bv.x, 0.f);
    s.y = fmaxf(s.y + bv.y, 0.f);
    s.z = fmaxf(s.z + bv.z, 0.f);
    s.w = fmaxf(s.w + bv.w, 0.f);
    *(float4*)&C[(size_t)i * 4] = s;
}

// ---------- one-pass ELL build ----------
__global__ __launch_bounds__(256) void scatter_ell(
    const int* __restrict__ row, const int* __restrict__ col,
    int* __restrict__ cnt, int* __restrict__ ell, int E)
{
    int e = blockIdx.x * 256 + threadIdx.x;
    if (e >= E) return;
    int r = row[e];
    int p = atomicAdd(&cnt[r], 1);
    if (p < 64) ell[(size_t)r * 64 + p] = col[e];
}

// ---------- gather-sum over ELL (layer 2, D=64) ----------
template<int DQ>
__global__ __launch_bounds__(256) void gather_sum_ell(
    const int* __restrict__ ell, const int* __restrict__ cnt,
    const float* __restrict__ z, float* __restrict__ h, int N)
{
    constexpr int GPB = 256 / DQ;
    const int node = blockIdx.x * GPB + threadIdx.x / DQ;
    const int lane = threadIdx.x % DQ;
    if (node >= N) return;
    const int deg = cnt[node];
    const size_t base = (size_t)node * 64;
    float ax = 0.f, ay = 0.f, az = 0.f, aw = 0.f;
    for (int b0 = 0; b0 < deg; b0 += DQ) {
        int c = (b0 + lane < deg) ? ell[base + b0 + lane] : 0;
        int m = min(DQ, deg - b0);
        for (int j = 0; j < m; ++j) {
            int cj = __shfl(c, j, DQ);
            float4 zv = *(const float4*)&z[(size_t)cj * (DQ * 4) + lane * 4];
            ax += zv.x; ay += zv.y; az += zv.z; aw += zv.w;
        }
    }
    *(float4*)&h[(size_t)node * (DQ * 4) + lane * 4] = make_float4(ax, ay, az, aw);
}

// ---------- sorted-batch mean pool ----------
__global__ __launch_bounds__(256) void bounds_kernel(
    const int* __restrict__ batch, int* __restrict__ bstart, int N, int B)
{
    int b = blockIdx.x * 256 + threadIdx.x;
    if (b > B) return;
    int lo = 0, hi = N;
    while (lo < hi) {
        int mid = (lo + hi) >> 1;
        if (batch[mid] < b) lo = mid + 1; else hi = mid;
    }
    bstart[b] = lo;
}

__global__ __launch_bounds__(256) void pool_sorted(
    const float* __restrict__ h2, const int* __restrict__ bstart,
    float* __restrict__ g)
{
    __shared__ float4 s[256];
    const int b  = blockIdx.x;
    const int c4 = threadIdx.x & 15;
    const int rg = threadIdx.x >> 4;
    const int start = bstart[b], end = bstart[b + 1];
    float4 acc = make_float4(0.f, 0.f, 0.f, 0.f);
    for (int r = start + rg; r < end; r += 16) {
        float4 v = *(const float4*)&h2[(size_t)r * 64 + c4 * 4];
        acc.x += v.x; acc.y += v.y; acc.z += v.z; acc.w += v.w;
    }
    s[threadIdx.x] = acc;
    __syncthreads();
    #pragma unroll
    for (int off = 8; off >= 1; off >>= 1) {
        if (rg < off) {
            float4 o = s[(rg + off) * 16 + c4];
            float4 m = s[rg * 16 + c4];
            m.x += o.x; m.y += o.y; m.z += o.z; m.w += o.w;
            s[rg * 16 + c4] = m;
        }
        __syncthreads();
    }
    if (rg == 0) {
        float inv = 1.0f / fmaxf((float)(end - start), 1.0f);
        float4 m = s[c4];
        m.x *= inv; m.y *= inv; m.z *= inv; m.w *= inv;
        *(float4*)&g[(size_t)b * 64 + c4 * 4] = m;
    }
}

// out[512,4] = softmax( A[512,1024] @ W[4,1024]^T + bias )
__global__ __launch_bounds__(256) void final_kernel(
    const float* __restrict__ A, const float* __restrict__ W,
    const float* __restrict__ bias, float* __restrict__ out)
{
    int i = blockIdx.x * 256 + threadIdx.x;
    int r = i >> 2, o = i & 3;
    float s = bias[o];
    const float4* a = (const float4*)&A[(size_t)r * 1024];
    const float4* w = (const float4*)&W[(size_t)o * 1024];
    #pragma unroll 4
    for (int k = 0; k < 256; ++k) {
        float4 av = a[k], wv = w[k];
        s += av.x * wv.x + av.y * wv.y + av.z * wv.z + av.w * wv.w;
    }
    float m = s;
    m = fmaxf(m, __shfl_xor(m, 1));
    m = fmaxf(m, __shfl_xor(m, 2));
    float e = __expf(s - m);
    float sum = e;
    sum += __shfl_xor(sum, 1);
    sum += __shfl_xor(sum, 2);
    out[i] = e / sum;
}

extern "C" void kernel_launch(void* const* d_in, const int* in_sizes, int n_in,
                              void* d_out, int out_size, void* d_ws, size_t ws_size,
                              hipStream_t stream)
{
    const float* x     = (const float*)d_in[0];
    const int*   ei    = (const int*)d_in[1];
    const int*   batch = (const int*)d_in[2];
    const float* fc1_w = (const float*)d_in[3];   // [4,32,128] -> [128,128]
    const float* fc2_w = (const float*)d_in[5];   // [1,64,128] -> [64,128]
    const float* w1 = (const float*)d_in[7];  const float* b1 = (const float*)d_in[8];
    const float* w2 = (const float*)d_in[9];  const float* b2 = (const float*)d_in[10];
    const float* w3 = (const float*)d_in[11]; const float* b3 = (const float*)d_in[12];
    const float* w4 = (const float*)d_in[13]; const float* b4 = (const float*)d_in[14];
    const float* w5 = (const float*)d_in[15]; const float* b5 = (const float*)d_in[16];
    float* out = (float*)d_out;

    const int N = 50000, E = 800000, B = 512;
    const int* rowp = ei;        // destinations
    const int* colp = ei + E;    // sources

    // ---- workspace layout ----
    // bufB: ELL (3.2M ints) | z2 (3.2M floats)     -> cpart (MLP partials)
    // bufA: h2 (3.2M floats) | a1,a2 (MLP)
    float* ws   = (float*)d_ws;
    float* bufA = ws;
    float* bufB = ws + 6400000;
    float* g    = ws + 12800000;              // 32768 f
    int* cnt    = (int*)(g + 32768);          // 50000
    int* bstart = cnt + 50000;                // 513

    int*   ell   = (int*)bufB;                // 50000*64 ints
    float* z2    = bufB + 3200000;            // 50000*64 floats
    float* h2    = bufA;                      // 50000*64 floats
    float* a1    = bufA + 3200000;            // 524288
    float* a2    = a1 + 524288;               // 524288
    float* cpart = bufB;                      // 8*524288 (ELL/z2 dead by then)

    // ---- build ELL adjacency + graph bounds ----
    hipMemsetAsync(cnt, 0, (size_t)N * sizeof(int), stream);
    scatter_ell<<<(E + 255) / 256, 256, 0, stream>>>(rowp, colp, cnt, ell, E);
    bounds_kernel<<<3, 256, 0, stream>>>(batch, bstart, N, B);

    // ---- fused layers 1+2 GEMMs: z2 = elu(gather(x)@W1^T)@W2^T ----
    gat_layer12<<<782, 256, 0, stream>>>(ell, cnt, x, fc1_w, fc2_w, z2, N);

    // ---- h2 = gather-sum(z2) ----
    gather_sum_ell<16><<<(N + 15) / 16, 256, 0, stream>>>(ell, cnt, z2, h2, N);

    // ---- mean-pool by graph ----
    pool_sorted<<<B, 256, 0, stream>>>(h2, bstart, g);

    // ---- MLP ----
    gemm256<1, true, false><<<dim3(8, 16, 1), 256, 0, stream>>>(g, w1, b1, a1, 512, 1024, 64, 0);
    gemm256<0, false, true><<<dim3(8, 16, 8), 256, 0, stream>>>(a1, w2, nullptr, cpart, 512, 1024, 1024, 128);
    reduce_bias_relu<<<512, 256, 0, stream>>>(cpart, b2, a2, 131072, 1024, 8);
    gemm256<0, false, true><<<dim3(8, 16, 8), 256, 0, stream>>>(a2, w3, nullptr, cpart, 512, 1024, 1024, 128);
    reduce_bias_relu<<<512, 256, 0, stream>>>(cpart, b3, a1, 131072, 1024, 8);
    gemm256<0, false, true><<<dim3(8, 16, 8), 256, 0, stream>>>(a1, w4, nullptr, cpart, 512, 1024, 1024, 128);
    reduce_bias_relu<<<512, 256, 0, stream>>>(cpart, b4, a2, 131072, 1024, 8);

    // ---- final layer + softmax ----
    final_kernel<<<8, 256, 0, stream>>>(a2, w5, b5, out);
}

// Round 7
// 329.995 us; speedup vs baseline: 1.1224x; 1.1224x over previous
//
#include <hip/hip_runtime.h>
#include <hip/hip_bf16.h>

__device__ __forceinline__ float eluf(float x) {
    return x > 0.f ? x : expm1f(x);
}

// C[M,N] = act( A'[M,K] @ B[N,K]^T + bias ), A' = ELU_A ? elu(A) : A
// ACT: 0 none, 1 relu.  SPLIT: raw partial to C + blockIdx.z*M*N
template<bool ELU_A, int ACT, bool BIAS, bool SPLIT>
__global__ __launch_bounds__(256) void gemm256(
    const float* __restrict__ A, const float* __restrict__ B,
    const float* __restrict__ bias, float* __restrict__ C,
    int M, int N, int K, int kChunk)
{
    constexpr int BM = 64, BN = 64, BK = 16;
    __shared__ float As[BK][BM + 4];
    __shared__ float Bs[BK][BN + 4];
    const int t  = threadIdx.x;
    const int tx = t & 15;
    const int ty = t >> 4;
    const int m0 = blockIdx.x * BM;
    const int n0 = blockIdx.y * BN;
    const int kBeg = SPLIT ? blockIdx.z * kChunk : 0;
    const int kEnd = SPLIT ? kBeg + kChunk : K;

    const int sr = t >> 2;
    const int sc = t & 3;

    float acc[4][4] = {};

    for (int k0 = kBeg; k0 < kEnd; k0 += BK) {
        {
            int row = m0 + sr;
            float4 v = make_float4(0.f, 0.f, 0.f, 0.f);
            if (row < M) v = *(const float4*)&A[(size_t)row * K + k0 + sc * 4];
            if (ELU_A) { v.x = eluf(v.x); v.y = eluf(v.y); v.z = eluf(v.z); v.w = eluf(v.w); }
            As[sc * 4 + 0][sr] = v.x; As[sc * 4 + 1][sr] = v.y;
            As[sc * 4 + 2][sr] = v.z; As[sc * 4 + 3][sr] = v.w;
        }
        {
            float4 v = *(const float4*)&B[(size_t)(n0 + sr) * K + k0 + sc * 4];
            Bs[sc * 4 + 0][sr] = v.x; Bs[sc * 4 + 1][sr] = v.y;
            Bs[sc * 4 + 2][sr] = v.z; Bs[sc * 4 + 3][sr] = v.w;
        }
        __syncthreads();
        #pragma unroll
        for (int k = 0; k < BK; ++k) {
            float a[4], b[4];
            *(float4*)&a[0] = *(const float4*)&As[k][ty * 4];
            *(float4*)&b[0] = *(const float4*)&Bs[k][tx * 4];
            #pragma unroll
            for (int i = 0; i < 4; ++i)
                #pragma unroll
                for (int j = 0; j < 4; ++j)
                    acc[i][j] = fmaf(a[i], b[j], acc[i][j]);
        }
        __syncthreads();
    }

    float* Cw = SPLIT ? C + (size_t)blockIdx.z * M * N : C;
    #pragma unroll
    for (int i = 0; i < 4; ++i) {
        int row = m0 + ty * 4 + i;
        if (row >= M) continue;
        float4 v;
        float* vp = (float*)&v;
        #pragma unroll
        for (int j = 0; j < 4; ++j) {
            float xv = acc[i][j];
            if (!SPLIT) {
                if (BIAS) xv += bias[n0 + tx * 4 + j];
                if (ACT == 1) xv = fmaxf(xv, 0.f);
            }
            vp[j] = xv;
        }
        *(float4*)&Cw[(size_t)row * N + n0 + tx * 4] = v;
    }
}

// In-place A[m0:m0+64, :] = A_tile @ W^T, K = N = 128.
// W streamed in 16-k LDS tiles (42 KB total -> 3 blocks/CU),
// conflict-free column ownership tx+16*j, float4 epilogue via LDS staging.
__global__ __launch_bounds__(256) void gemm_inplace_128(
    float* __restrict__ A, const float* __restrict__ W, int M)
{
    __shared__ float As[64][132];   // 33.8 KB  [row][k]
    __shared__ float Ws[16][132];   //  8.4 KB  [k][n]
    const int t  = threadIdx.x;
    const int m0 = blockIdx.x * 64;

    for (int idx = t; idx < 2048; idx += 256) {      // 64 rows x 32 float4
        int row = idx >> 5, c4 = idx & 31;
        int grow = m0 + row;
        float4 v = make_float4(0.f, 0.f, 0.f, 0.f);
        if (grow < M) v = *(const float4*)&A[(size_t)grow * 128 + c4 * 4];
        *(float4*)&As[row][c4 * 4] = v;
    }
    __syncthreads();

    const int tx = t & 15, ty = t >> 4;   // rows ty*4+i, cols tx+16*j
    float acc[4][8] = {};
    for (int k0 = 0; k0 < 128; k0 += 16) {
        for (int idx = t; idx < 512; idx += 256) {   // 128 n x 4 kq
            int n = idx >> 2, kq = idx & 3;
            float4 v = *(const float4*)&W[(size_t)n * 128 + k0 + kq * 4];
            Ws[kq * 4 + 0][n] = v.x; Ws[kq * 4 + 1][n] = v.y;
            Ws[kq * 4 + 2][n] = v.z; Ws[kq * 4 + 3][n] = v.w;
        }
        __syncthreads();
        #pragma unroll
        for (int k = 0; k < 16; ++k) {
            float a[4], w[8];
            #pragma unroll
            for (int i = 0; i < 4; ++i) a[i] = As[ty * 4 + i][k0 + k];
            #pragma unroll
            for (int j = 0; j < 8; ++j) w[j] = Ws[k][tx + 16 * j];
            #pragma unroll
            for (int i = 0; i < 4; ++i)
                #pragma unroll
                for (int j = 0; j < 8; ++j)
                    acc[i][j] = fmaf(a[i], w[j], acc[i][j]);
        }
        __syncthreads();
    }

    // stage result through As (all As reads complete), then float4 stores
    #pragma unroll
    for (int i = 0; i < 4; ++i)
        #pragma unroll
        for (int j = 0; j < 8; ++j)
            As[ty * 4 + i][tx + 16 * j] = acc[i][j];
    __syncthreads();
    for (int idx = t; idx < 2048; idx += 256) {
        int row = idx >> 5, c4 = idx & 31;
        int grow = m0 + row;
        if (grow < M)
            *(float4*)&A[(size_t)grow * 128 + c4 * 4] = *(const float4*)&As[row][c4 * 4];
    }
}

// C[i] = relu( sum_z part[z][i] + bias[i % N] ), float4-wide
__global__ __launch_bounds__(256) void reduce_bias_relu(
    const float* __restrict__ part, const float* __restrict__ bias,
    float* __restrict__ C, int MN4, int N, int KS)
{
    int i = blockIdx.x * 256 + threadIdx.x;
    if (i >= MN4) return;
    float4 s = *(const float4*)&part[(size_t)i * 4];
    for (int z = 1; z < KS; ++z) {
        float4 p = *(const float4*)&part[(size_t)z * MN4 * 4 + (size_t)i * 4];
        s.x += p.x; s.y += p.y; s.z += p.z; s.w += p.w;
    }
    float4 bv = *(const float4*)&bias[(i * 4) & (N - 1)];
    s.x = fmaxf(s.x + bv.x, 0.f);
    s.y = fmaxf(s.y + bv.y, 0.f);
    s.z = fmaxf(s.z + bv.z, 0.f);
    s.w = fmaxf(s.w + bv.w, 0.f);
    *(float4*)&C[(size_t)i * 4] = s;
}

// ---------- one-pass ELL build ----------
__global__ __launch_bounds__(256) void scatter_ell(
    const int* __restrict__ row, const int* __restrict__ col,
    int* __restrict__ cnt, int* __restrict__ ell, int E)
{
    int e = blockIdx.x * 256 + threadIdx.x;
    if (e >= E) return;
    int r = row[e];
    int p = atomicAdd(&cnt[r], 1);
    if (p < 64) ell[(size_t)r * 64 + p] = col[e];
}

// ---------- gather-sum over ELL:  h[n] = sum_j z[ell[n][j]] ----------
template<int DQ>   // DQ lanes per node, D = DQ*4
__global__ __launch_bounds__(256) void gather_sum_ell(
    const int* __restrict__ ell, const int* __restrict__ cnt,
    const float* __restrict__ z, float* __restrict__ h, int N)
{
    constexpr int GPB = 256 / DQ;
    const int node = blockIdx.x * GPB + threadIdx.x / DQ;
    const int lane = threadIdx.x % DQ;
    if (node >= N) return;
    const int deg = cnt[node];
    const size_t base = (size_t)node * 64;
    float ax = 0.f, ay = 0.f, az = 0.f, aw = 0.f;
    for (int b0 = 0; b0 < deg; b0 += DQ) {
        int c = (b0 + lane < deg) ? ell[base + b0 + lane] : 0;
        int m = min(DQ, deg - b0);
        for (int j = 0; j < m; ++j) {
            int cj = __shfl(c, j, DQ);
            float4 zv = *(const float4*)&z[(size_t)cj * (DQ * 4) + lane * 4];
            ax += zv.x; ay += zv.y; az += zv.z; aw += zv.w;
        }
    }
    *(float4*)&h[(size_t)node * (DQ * 4) + lane * 4] = make_float4(ax, ay, az, aw);
}

// ---------- sorted-batch mean pool ----------
__global__ __launch_bounds__(256) void bounds_kernel(
    const int* __restrict__ batch, int* __restrict__ bstart, int N, int B)
{
    int b = blockIdx.x * 256 + threadIdx.x;
    if (b > B) return;
    int lo = 0, hi = N;
    while (lo < hi) {
        int mid = (lo + hi) >> 1;
        if (batch[mid] < b) lo = mid + 1; else hi = mid;
    }
    bstart[b] = lo;
}

__global__ __launch_bounds__(256) void pool_sorted(
    const float* __restrict__ h2, const int* __restrict__ bstart,
    float* __restrict__ g)
{
    __shared__ float4 s[256];
    const int b  = blockIdx.x;
    const int c4 = threadIdx.x & 15;
    const int rg = threadIdx.x >> 4;
    const int start = bstart[b], end = bstart[b + 1];
    float4 acc = make_float4(0.f, 0.f, 0.f, 0.f);
    for (int r = start + rg; r < end; r += 16) {
        float4 v = *(const float4*)&h2[(size_t)r * 64 + c4 * 4];
        acc.x += v.x; acc.y += v.y; acc.z += v.z; acc.w += v.w;
    }
    s[threadIdx.x] = acc;
    __syncthreads();
    #pragma unroll
    for (int off = 8; off >= 1; off >>= 1) {
        if (rg < off) {
            float4 o = s[(rg + off) * 16 + c4];
            float4 m = s[rg * 16 + c4];
            m.x += o.x; m.y += o.y; m.z += o.z; m.w += o.w;
            s[rg * 16 + c4] = m;
        }
        __syncthreads();
    }
    if (rg == 0) {
        float inv = 1.0f / fmaxf((float)(end - start), 1.0f);
        float4 m = s[c4];
        m.x *= inv; m.y *= inv; m.z *= inv; m.w *= inv;
        *(float4*)&g[(size_t)b * 64 + c4 * 4] = m;
    }
}

// out[512,4] = softmax( A[512,1024] @ W[4,1024]^T + bias )
__global__ __launch_bounds__(256) void final_kernel(
    const float* __restrict__ A, const float* __restrict__ W,
    const float* __restrict__ bias, float* __restrict__ out)
{
    int i = blockIdx.x * 256 + threadIdx.x;
    int r = i >> 2, o = i & 3;
    float s = bias[o];
    const float4* a = (const float4*)&A[(size_t)r * 1024];
    const float4* w = (const float4*)&W[(size_t)o * 1024];
    #pragma unroll 4
    for (int k = 0; k < 256; ++k) {
        float4 av = a[k], wv = w[k];
        s += av.x * wv.x + av.y * wv.y + av.z * wv.z + av.w * wv.w;
    }
    float m = s;
    m = fmaxf(m, __shfl_xor(m, 1));
    m = fmaxf(m, __shfl_xor(m, 2));
    float e = __expf(s - m);
    float sum = e;
    sum += __shfl_xor(sum, 1);
    sum += __shfl_xor(sum, 2);
    out[i] = e / sum;
}

extern "C" void kernel_launch(void* const* d_in, const int* in_sizes, int n_in,
                              void* d_out, int out_size, void* d_ws, size_t ws_size,
                              hipStream_t stream)
{
    const float* x     = (const float*)d_in[0];
    const int*   ei    = (const int*)d_in[1];
    const int*   batch = (const int*)d_in[2];
    const float* fc1_w = (const float*)d_in[3];   // [4,32,128] -> [128,128]
    const float* fc2_w = (const float*)d_in[5];   // [1,64,128] -> [64,128]
    const float* w1 = (const float*)d_in[7];  const float* b1 = (const float*)d_in[8];
    const float* w2 = (const float*)d_in[9];  const float* b2 = (const float*)d_in[10];
    const float* w3 = (const float*)d_in[11]; const float* b3 = (const float*)d_in[12];
    const float* w4 = (const float*)d_in[13]; const float* b4 = (const float*)d_in[14];
    const float* w5 = (const float*)d_in[15]; const float* b5 = (const float*)d_in[16];
    float* out = (float*)d_out;

    const int N = 50000, E = 800000, B = 512;
    const int* rowp = ei;        // destinations
    const int* colp = ei + E;    // sources

    // ---- workspace layout ----
    // bufA [6.4M f]: gx -> h1 (in place) ; later h2 (first 3.2M) + a1/a2
    // bufB [6.4M f]: ELL (3.2M ints) | z2 (3.2M floats) ; later cpart
    float* ws   = (float*)d_ws;
    float* bufA = ws;
    float* bufB = ws + 6400000;
    float* g    = ws + 12800000;              // 32768 f
    int* cnt    = (int*)(g + 32768);          // 50000
    int* bstart = cnt + 50000;                // 513

    int*   ell   = (int*)bufB;                // 50000*64 ints
    float* z2    = bufB + 3200000;            // 50000*64 floats
    float* h2    = bufA;                      // 50000*64 floats (h1 dead)
    float* a1    = bufA + 3200000;            // 524288
    float* a2    = a1 + 524288;               // 524288
    float* cpart = bufB;                      // 8*524288 (ELL/z2 dead by then)

    // ---- build ELL adjacency + graph bounds ----
    hipMemsetAsync(cnt, 0, (size_t)N * sizeof(int), stream);
    scatter_ell<<<(E + 255) / 256, 256, 0, stream>>>(rowp, colp, cnt, ell, E);
    bounds_kernel<<<3, 256, 0, stream>>>(batch, bstart, N, B);

    // ---- layer 1:  h1 = (gather-sum x) @ W1^T  (linearity) ----
    gather_sum_ell<32><<<(N + 7) / 8, 256, 0, stream>>>(ell, cnt, x, bufA, N);
    gemm_inplace_128<<<782, 256, 0, stream>>>(bufA, fc1_w, N);

    // ---- layer 2:  z2 = elu(h1) @ W2^T ; h2 = gather-sum(z2) ----
    gemm256<true, 0, false, false><<<dim3(782, 1, 1), 256, 0, stream>>>(bufA, fc2_w, nullptr, z2, N, 64, 128, 0);
    gather_sum_ell<16><<<(N + 15) / 16, 256, 0, stream>>>(ell, cnt, z2, h2, N);

    // ---- mean-pool by graph ----
    pool_sorted<<<B, 256, 0, stream>>>(h2, bstart, g);

    // ---- MLP ----
    gemm256<false, 1, true, false><<<dim3(8, 16, 1), 256, 0, stream>>>(g, w1, b1, a1, 512, 1024, 64, 0);
    gemm256<false, 0, false, true><<<dim3(8, 16, 8), 256, 0, stream>>>(a1, w2, nullptr, cpart, 512, 1024, 1024, 128);
    reduce_bias_relu<<<512, 256, 0, stream>>>(cpart, b2, a2, 131072, 1024, 8);
    gemm256<false, 0, false, true><<<dim3(8, 16, 8), 256, 0, stream>>>(a2, w3, nullptr, cpart, 512, 1024, 1024, 128);
    reduce_bias_relu<<<512, 256, 0, stream>>>(cpart, b3, a1, 131072, 1024, 8);
    gemm256<false, 0, false, true><<<dim3(8, 16, 8), 256, 0, stream>>>(a1, w4, nullptr, cpart, 512, 1024, 1024, 128);
    reduce_bias_relu<<<512, 256, 0, stream>>>(cpart, b4, a2, 131072, 1024, 8);

    // ---- final layer + softmax ----
    final_kernel<<<8, 256, 0, stream>>>(a2, w5, b5, out);
}